// Round 1
// baseline (409.234 us; speedup 1.0000x reference)
//
#include <hip/hip_runtime.h>

// LocalRefinedAttention on MI355X (gfx950), fused per-patch f16-MFMA kernel.
//
// Geometry: B=4, C=64, H=W=192, PS=8, STRIDE=4, PAD=2, NHEADS=4, head_dim=16.
// nH=nW=48, L=2304 patches/batch, 9216 patches total.
// Token reinterpretation: tok[t][d] = xpad[b, c=t, i*4+ (d>>3), j*4 + (d&7)]
// (token index = channel, feature index = spatial offset). Output channel = t,
// output spatial offset = projection output index c.

typedef _Float16 f16;
typedef _Float16 f16x4 __attribute__((ext_vector_type(4)));
typedef _Float16 f16x8 __attribute__((ext_vector_type(8)));
typedef float    f32x4 __attribute__((ext_vector_type(4)));

#define NHP 48                 // patch grid per side
#define LPB (NHP * NHP)        // 2304 patches per batch image
#define NPATCH (4 * LPB)       // 9216
#define LP 72                  // LDS row pitch in f16 (144 B: 16B-aligned rows, breaks 32-bank stride)

// ---- weight fp32 -> f16 conversion (runs every launch; deterministic) ----
__global__ __launch_bounds__(256) void wcvt_kernel(
    const float* __restrict__ wq, const float* __restrict__ wk,
    const float* __restrict__ wv, const float* __restrict__ wp,
    f16* __restrict__ wh)
{
    const int idx = blockIdx.x * 256 + threadIdx.x;   // 0..16383
    const int m = idx >> 12;
    const int r = idx & 4095;
    const float* src = (m == 0) ? wq : (m == 1) ? wk : (m == 2) ? wv : wp;
    wh[idx] = (f16)src[r];
}

// ---- main fused kernel: one workgroup (4 waves) per patch ----
__global__ __launch_bounds__(256, 4) void patch_attn_kernel(
    const float* __restrict__ x, const f16* __restrict__ wh,
    float* __restrict__ out)
{
    // 4 x 9216 B = 36 KiB -> 4 workgroups/CU (LDS-bound occupancy)
    __shared__ f16 Xs[64 * LP];   // X tokens; reused as O after attention
    __shared__ f16 Qs[64 * LP];
    __shared__ f16 Ks[64 * LP];
    __shared__ f16 Vs[64 * LP];

    const int pid = blockIdx.x;
    const int b   = pid / LPB;
    const int rem = pid - b * LPB;
    const int ib  = rem / NHP;
    const int jb  = rem - ib * NHP;
    const int r0  = ib * 4 - 2;   // top row in unpadded coords (may be <0)
    const int c0  = jb * 4 - 2;

    const int tid  = threadIdx.x;
    const int wv_  = tid >> 6;    // wave id 0..3
    const int lane = tid & 63;
    const int lr   = lane & 15;   // row-slot within 16x16 fragment
    const int lg   = lane >> 4;   // k-group 0..3

    // ---------- Phase 0: stage X (f16) ----------
    {
        const bool colok = (c0 >= 0) && (c0 + 7 < 192);
        for (int pp = tid; pp < 512; pp += 256) {       // (t, patch-row) pairs
            const int t  = pp >> 3;
            const int pr = pp & 7;
            const int rr = r0 + pr;
            f16x8 vals;
            #pragma unroll
            for (int q = 0; q < 8; ++q) vals[q] = (f16)0.f;
            if (rr >= 0 && rr < 192) {
                const float* src = x + ((size_t)((b * 64 + t) * 192 + rr)) * 192;
                if (colok) {
                    #pragma unroll
                    for (int q = 0; q < 4; ++q) {       // c0 is even -> 8B aligned
                        const float2 v2 = *(const float2*)(src + c0 + 2 * q);
                        vals[2 * q]     = (f16)v2.x;
                        vals[2 * q + 1] = (f16)v2.y;
                    }
                } else {
                    #pragma unroll
                    for (int q = 0; q < 8; ++q) {
                        const int cc = c0 + q;
                        if (cc >= 0 && cc < 192) vals[q] = (f16)src[cc];
                    }
                }
            }
            *(f16x8*)&Xs[t * LP + pr * 8] = vals;
        }
    }
    __syncthreads();

    // ---------- Phase 1: Q/K/V projections (wave = token tile) ----------
    // A-frag (16x16x32): lane holds X[row=lr][k = lg*8 + i]
    {
        const int trow = (wv_ * 16 + lr) * LP;
        const f16x8 xa0 = *(const f16x8*)&Xs[trow + lg * 8];
        const f16x8 xa1 = *(const f16x8*)&Xs[trow + 32 + lg * 8];

        f16* const dsts[3] = {Qs, Ks, Vs};
        #pragma unroll
        for (int m = 0; m < 3; ++m) {
            const f16* wb = wh + m * 4096;
            f32x4 acc[4];
            #pragma unroll
            for (int dj = 0; dj < 4; ++dj) acc[dj] = (f32x4){0.f, 0.f, 0.f, 0.f};
            #pragma unroll
            for (int dj = 0; dj < 4; ++dj) {
                const f16x8 b0 = *(const f16x8*)&wb[(dj * 16 + lr) * 64 + lg * 8];
                const f16x8 b1 = *(const f16x8*)&wb[(dj * 16 + lr) * 64 + 32 + lg * 8];
                acc[dj] = __builtin_amdgcn_mfma_f32_16x16x32_f16(xa0, b0, acc[dj], 0, 0, 0);
                acc[dj] = __builtin_amdgcn_mfma_f32_16x16x32_f16(xa1, b1, acc[dj], 0, 0, 0);
            }
            f16* dst = dsts[m];
            const float scl = (m == 0) ? 0.25f : 1.f;   // fold attention SCALE into Q
            #pragma unroll
            for (int dj = 0; dj < 4; ++dj) {
                #pragma unroll
                for (int rg = 0; rg < 4; ++rg) {
                    // C layout: col=lr, row=lg*4+rg (within tile)
                    dst[(wv_ * 16 + lg * 4 + rg) * LP + dj * 16 + lr] =
                        (f16)(acc[dj][rg] * scl);
                }
            }
        }
    }
    __syncthreads();

    // ---------- Phase 2: attention (wave = head) ----------
    const int h16 = wv_ * 16;
    {
        // S^T = mfma(A=K, B=Q): lane holds S[q = tj*16+lr][key = ti*16+lg*4+reg]
        f16x4 kf[4], qf[4];
        #pragma unroll
        for (int t4 = 0; t4 < 4; ++t4) {
            kf[t4] = *(const f16x4*)&Ks[(t4 * 16 + lr) * LP + h16 + lg * 4];
            qf[t4] = *(const f16x4*)&Qs[(t4 * 16 + lr) * LP + h16 + lg * 4];
        }
        f32x4 s[4][4];
        #pragma unroll
        for (int ti = 0; ti < 4; ++ti) {
            #pragma unroll
            for (int tj = 0; tj < 4; ++tj) {
                const f32x4 z = (f32x4){0.f, 0.f, 0.f, 0.f};
                s[ti][tj] = __builtin_amdgcn_mfma_f32_16x16x16f16(kf[ti], qf[tj], z, 0, 0, 0);
            }
        }

        // Row softmax: per query row, 16 local values + reduce over lanes l^16, l^32.
        f16x4 pf[4][4];   // P packed as A-frags for 16x16x16 PV mfma
        #pragma unroll
        for (int tj = 0; tj < 4; ++tj) {
            float mx = -1e30f;
            #pragma unroll
            for (int ti = 0; ti < 4; ++ti) {
                #pragma unroll
                for (int rg = 0; rg < 4; ++rg) mx = fmaxf(mx, s[ti][tj][rg]);
            }
            mx = fmaxf(mx, __shfl_xor(mx, 16, 64));
            mx = fmaxf(mx, __shfl_xor(mx, 32, 64));
            float sum = 0.f;
            #pragma unroll
            for (int ti = 0; ti < 4; ++ti) {
                #pragma unroll
                for (int rg = 0; rg < 4; ++rg) {
                    const float e = __expf(s[ti][tj][rg] - mx);
                    s[ti][tj][rg] = e;
                    sum += e;
                }
            }
            sum += __shfl_xor(sum, 16, 64);
            sum += __shfl_xor(sum, 32, 64);
            const float rs = __builtin_amdgcn_rcpf(sum);
            #pragma unroll
            for (int ti = 0; ti < 4; ++ti) {
                #pragma unroll
                for (int rg = 0; rg < 4; ++rg)
                    pf[ti][tj][rg] = (f16)(s[ti][tj][rg] * rs);
            }
        }

        // V B-frags: lane holds V[key = ks*16 + lg*4 + i][d = h16 + lr]
        f16x4 vf[4];
        #pragma unroll
        for (int ks = 0; ks < 4; ++ks) {
            #pragma unroll
            for (int i = 0; i < 4; ++i)
                vf[ks][i] = Vs[(ks * 16 + lg * 4 + i) * LP + h16 + lr];
        }

        f32x4 o[4];
        #pragma unroll
        for (int tj = 0; tj < 4; ++tj) o[tj] = (f32x4){0.f, 0.f, 0.f, 0.f};
        #pragma unroll
        for (int tj = 0; tj < 4; ++tj) {
            #pragma unroll
            for (int ks = 0; ks < 4; ++ks)
                o[tj] = __builtin_amdgcn_mfma_f32_16x16x16f16(pf[ks][tj], vf[ks], o[tj], 0, 0, 0);
        }

        // O -> LDS (reuse Xs; its last read was before the phase-1 barrier)
        #pragma unroll
        for (int tj = 0; tj < 4; ++tj) {
            #pragma unroll
            for (int rg = 0; rg < 4; ++rg)
                Xs[(tj * 16 + lg * 4 + rg) * LP + h16 + lr] = (f16)o[tj][rg];
        }
    }
    __syncthreads();

    // ---------- Phase 3: output projection + scatter-add ----------
    {
        const int trow = (wv_ * 16 + lr) * LP;
        const f16x8 oa0 = *(const f16x8*)&Xs[trow + lg * 8];
        const f16x8 oa1 = *(const f16x8*)&Xs[trow + 32 + lg * 8];
        const f16* wpb = wh + 3 * 4096;
        f32x4 acc[4];
        #pragma unroll
        for (int cj = 0; cj < 4; ++cj) acc[cj] = (f32x4){0.f, 0.f, 0.f, 0.f};
        #pragma unroll
        for (int cj = 0; cj < 4; ++cj) {
            const f16x8 b0 = *(const f16x8*)&wpb[(cj * 16 + lr) * 64 + lg * 8];
            const f16x8 b1 = *(const f16x8*)&wpb[(cj * 16 + lr) * 64 + 32 + lg * 8];
            acc[cj] = __builtin_amdgcn_mfma_f32_16x16x32_f16(oa0, b0, acc[cj], 0, 0, 0);
            acc[cj] = __builtin_amdgcn_mfma_f32_16x16x32_f16(oa1, b1, acc[cj], 0, 0, 0);
        }
        #pragma unroll
        for (int cj = 0; cj < 4; ++cj) {
            #pragma unroll
            for (int rg = 0; rg < 4; ++rg) {
                const int t  = wv_ * 16 + lg * 4 + rg;  // output channel
                const int c  = cj * 16 + lr;            // spatial offset pi*8+pj
                const int rr = r0 + (c >> 3);
                const int cc = c0 + (c & 7);
                if (rr >= 0 && rr < 192 && cc >= 0 && cc < 192)
                    atomicAdd(&out[((size_t)(b * 64 + t) * 192 + rr) * 192 + cc],
                              acc[cj][rg]);
            }
        }
    }
}

// ---- final divide by analytic fold count: c(h)*c(w) in {1,2,4} ----
__global__ __launch_bounds__(256) void div_kernel(float* __restrict__ out)
{
    const int idx = blockIdx.x * 256 + threadIdx.x;   // grid covers exactly 4*64*192*192
    const int w = idx % 192;
    const int h = (idx / 192) % 192;
    const float ch = (h >= 2 && h <= 189) ? 2.f : 1.f;
    const float cw = (w >= 2 && w <= 189) ? 2.f : 1.f;
    out[idx] = out[idx] / (ch * cw + 1e-6f);
}

extern "C" void kernel_launch(void* const* d_in, const int* in_sizes, int n_in,
                              void* d_out, int out_size, void* d_ws, size_t ws_size,
                              hipStream_t stream)
{
    const float* x  = (const float*)d_in[0];
    const float* wq = (const float*)d_in[1];
    const float* wk = (const float*)d_in[2];
    const float* wv = (const float*)d_in[3];
    const float* wp = (const float*)d_in[4];
    float* out = (float*)d_out;
    f16* wh = (f16*)d_ws;   // 16384 f16 = 32 KiB of scratch

    // Output accumulates via atomics -> must re-zero every call.
    hipMemsetAsync(d_out, 0, (size_t)out_size * sizeof(float), stream);
    wcvt_kernel<<<64, 256, 0, stream>>>(wq, wk, wv, wp, wh);
    patch_attn_kernel<<<NPATCH, 256, 0, stream>>>(x, wh, out);
    div_kernel<<<36864, 256, 0, stream>>>(out);
}